// Round 5
// baseline (156.024 us; speedup 1.0000x reference)
//
#include <hip/hip_runtime.h>
#include <hip/hip_bf16.h>
#include <cstdint>
#include <cstddef>

// Problem constants: B=32, N=768, D=768
#define BN_ROWS 24576
#define DD 768
#define BE (768*768)
#define BM 384
#define BN_T 192
#define BK 32
#define ABUF 24576            // A region bytes per buffer (384 rows x 64B)
#define BUFSZ 36864           // A (24576) + B (12288)

typedef __attribute__((ext_vector_type(8))) short bf16x8;
typedef __attribute__((ext_vector_type(4))) float f32x4;

static __device__ __forceinline__ unsigned short f2bf(float f) {
  unsigned int u = __builtin_bit_cast(unsigned int, f);
  unsigned int lsb = (u >> 16) & 1u;
  u += 0x7fffu + lsb;
  return (unsigned short)(u >> 16);
}

// ---------------- conversion kernels ----------------

__global__ __launch_bounds__(256) void convertX(const float* __restrict__ x,
                                                unsigned short* __restrict__ xb, int n4) {
  int idx = blockIdx.x * blockDim.x + threadIdx.x;
  int stride = gridDim.x * blockDim.x;
  for (int i = idx; i < n4; i += stride) {
    float4 v = reinterpret_cast<const float4*>(x)[i];
    ushort4 o;
    o.x = f2bf(v.x); o.y = f2bf(v.y); o.z = f2bf(v.z); o.w = f2bf(v.w);
    reinterpret_cast<ushort4*>(xb)[i] = o;
  }
}

// Transpose+convert via LDS tile (coalesced loads AND stores).
// 144 blocks of 64x64, both matrices per block.
__global__ __launch_bounds__(256) void convertWT(const float* __restrict__ Wl,
                                                 const float* __restrict__ Wl1,
                                                 unsigned short* __restrict__ WlT,
                                                 unsigned short* __restrict__ Wl1T) {
  __shared__ float tile[64][65];
  int tr = blockIdx.x / 12, tc = blockIdx.x % 12;
  int c = threadIdx.x & 63, r0 = threadIdx.x >> 6;
  const float* srcs[2] = {Wl, Wl1};
  unsigned short* dsts[2] = {WlT, Wl1T};
  #pragma unroll
  for (int m = 0; m < 2; ++m) {
    const float* src = srcs[m];
    #pragma unroll
    for (int i = 0; i < 16; ++i) {
      int r = r0 + i * 4;
      tile[r][c] = src[(size_t)(tr * 64 + r) * DD + tc * 64 + c];
    }
    __syncthreads();
    unsigned short* dst = dsts[m];
    #pragma unroll
    for (int i = 0; i < 16; ++i) {
      int r2 = r0 + i * 4;
      dst[(size_t)(tc * 64 + r2) * DD + tr * 64 + c] = f2bf(tile[c][r2]);
    }
    __syncthreads();
  }
}

__global__ __launch_bounds__(256) void adjNorm(const float* __restrict__ adj,
                                               unsigned short* __restrict__ adjnb) {
  int wid = threadIdx.x >> 6, lane = threadIdx.x & 63;
  int row = blockIdx.x * 4 + wid;
  const float4* a = reinterpret_cast<const float4*>(adj + (size_t)row * DD);
  float4 v[3];
  float s = 0.f;
  #pragma unroll
  for (int i = 0; i < 3; ++i) {
    v[i] = a[i * 64 + lane];
    s += (v[i].x + v[i].y) + (v[i].z + v[i].w);
  }
  #pragma unroll
  for (int off = 32; off; off >>= 1) s += __shfl_down(s, off);
  s = __shfl(s, 0);
  float rinv = (s == 0.f) ? 0.f : 1.f / s;
  ushort4* o = reinterpret_cast<ushort4*>(adjnb + (size_t)row * DD);
  #pragma unroll
  for (int i = 0; i < 3; ++i) {
    ushort4 u;
    u.x = f2bf(v[i].x * rinv); u.y = f2bf(v[i].y * rinv);
    u.z = f2bf(v[i].z * rinv); u.w = f2bf(v[i].w * rinv);
    o[i * 64 + lane] = u;
  }
}

// -------- 8-wave 384x192 BK=32 triple-buffered deep-pipeline GEMM --------
// LDS: 3 buffers of 36864 B: A = 384 rows x 64B, B = 192 rows x 64B (after A).
// Tile t: stage(t+2) -> vmcnt(12|6) [counted, NEVER 0] -> s_barrier ->
//         12 ds_read_b128 -> 36 MFMA (setprio) -> s_barrier.
// Loads for tile t issued 2 tiles early -> HBM latency fully covered, VMEM
// pipelines behind MFMA (m218 T4 mechanism).
// Staging: waves 0-3 stage A (6 x 1KB), waves 4-7 stage B (3 x 1KB).
// Swizzle: 16B-slot XOR (row>>1)&3 (2 lanes/bank on frag reads = free),
// pre-applied on the global source; gload_lds dest linear (= base+lane*16).
// MODE 0: e1 = Xb @ W1T, transposed bf16 store (NT=24)
// MODE 1: out = leaky( adjnb@e1 + Xb@Wl ), fused 48-tile K-loop, fp32 store

template<int MODE>
__global__ __launch_bounds__(512, 2) void gemm8(
    const unsigned short* __restrict__ P0,  // MODE0: Xb     MODE1: adjnb
    const unsigned short* __restrict__ P1,  // MODE0: W1T    MODE1: e1T
    const unsigned short* __restrict__ P2,  // MODE1: Xb
    const unsigned short* __restrict__ P3,  // MODE1: WlT
    void* __restrict__ outp)
{
  __shared__ char smem[3 * BUFSZ];
  constexpr int NT = MODE ? 48 : 24;
  const int tid = threadIdx.x, lane = tid & 63;
  const int wid = tid >> 6, wr = wid >> 1, wc = wid & 1;

  // XCD-chunked logical block id (grid 256 = 8 XCD x 32)
  const int logical = (blockIdx.x & 7) * 32 + (blockIdx.x >> 3);

  const unsigned short *Ab0, *Bb0, *Ab1 = nullptr, *Bb1 = nullptr;
  int mt, nt, b;
  if (MODE == 0) {
    mt = logical >> 2; nt = logical & 3;          // mt 0..63, nt 0..3
    b = mt >> 1;
    Ab0 = P0 + (size_t)mt * BM * DD;
    Bb0 = P1 + (size_t)nt * BN_T * DD;
  } else {
    b = logical >> 3; int r = logical & 7; mt = r >> 2; nt = r & 3;
    size_t bo = (size_t)b * BE;
    Ab0 = P0 + bo + (size_t)mt * BM * DD;   // adjnb
    Bb0 = P1 + bo + (size_t)nt * BN_T * DD; // e1T
    Ab1 = P2 + bo + (size_t)mt * BM * DD;   // Xb
    Bb1 = P3 + (size_t)nt * BN_T * DD;      // WlT
  }

  const int r_in = lane >> 2;                 // row within 16-row chunk
  const int s_in = lane & 3;                  // 16B slot

  auto stage = [&](int s) {
    int sc = s < NT ? s : 0;                  // clamp keeps vmcnt uniform
    const int buf = (s % 3) * BUFSZ;
    const unsigned short *Abase, *Bbase;
    int kk;
    if (MODE == 1 && sc >= 24) { kk = sc - 24; Abase = Ab1; Bbase = Bb1; }
    else                       { kk = sc;      Abase = Ab0; Bbase = Bb0; }
    if (wid < 4) {
      #pragma unroll
      for (int i = 0; i < 6; ++i) {
        int row = wid * 96 + i * 16 + r_in;
        int slot = s_in ^ ((row >> 1) & 3);
        const unsigned short* src = Abase + (size_t)row * DD + kk * BK + slot * 8;
        __builtin_amdgcn_global_load_lds(
            (const __attribute__((address_space(1))) void*)src,
            (__attribute__((address_space(3))) void*)(smem + buf + (wid * 96 + i * 16) * 64),
            16, 0, 0);
      }
    } else {
      #pragma unroll
      for (int i = 0; i < 3; ++i) {
        int row = (wid - 4) * 48 + i * 16 + r_in;
        int slot = s_in ^ ((row >> 1) & 3);
        const unsigned short* src = Bbase + (size_t)row * DD + kk * BK + slot * 8;
        __builtin_amdgcn_global_load_lds(
            (const __attribute__((address_space(1))) void*)src,
            (__attribute__((address_space(3))) void*)(smem + buf + ABUF + ((wid - 4) * 48 + i * 16) * 64),
            16, 0, 0);
      }
    }
  };

  const int ks = lane >> 4;                   // k-slot 0..3 (8 elems each)
  auto frag = [&](int off, int row) -> bf16x8 {
    int slot = ks ^ ((row >> 1) & 3);
    return *reinterpret_cast<const bf16x8*>(smem + off + row * 64 + slot * 16);
  };

  f32x4 acc[6][6] = {};

  // prologue: 2 tiles in flight
  stage(0); stage(1);

  for (int t = 0; t < NT; ++t) {
    stage(t + 2);
    if (wid < 4) asm volatile("s_waitcnt vmcnt(12)" ::: "memory");
    else         asm volatile("s_waitcnt vmcnt(6)"  ::: "memory");
    __builtin_amdgcn_s_barrier();

    const int bufA = (t % 3) * BUFSZ;
    const int bufB = bufA + ABUF;
    bf16x8 af[6], bg[6];
    #pragma unroll
    for (int i = 0; i < 6; ++i) {
      af[i] = frag(bufA, wr * 96 + i * 16 + (lane & 15));
      bg[i] = frag(bufB, wc * 96 + i * 16 + (lane & 15));
    }
    __builtin_amdgcn_s_setprio(1);
    #pragma unroll
    for (int mi = 0; mi < 6; ++mi)
      #pragma unroll
      for (int ni = 0; ni < 6; ++ni)
        acc[mi][ni] = __builtin_amdgcn_mfma_f32_16x16x32_bf16(af[mi], bg[ni], acc[mi][ni], 0, 0, 0);
    __builtin_amdgcn_s_setprio(0);
    __builtin_amdgcn_s_barrier();
  }

  // ---------------- epilogue ----------------
  if (MODE == 0) {
    unsigned short* ob = (unsigned short*)outp + (size_t)b * BE;
    const int mloc = (mt & 1) * BM + wr * 96 + (lane >> 4) * 4;
    #pragma unroll
    for (int mi = 0; mi < 6; ++mi)
      #pragma unroll
      for (int ni = 0; ni < 6; ++ni) {
        int m = mloc + mi * 16;
        int d = nt * BN_T + wc * 96 + ni * 16 + (lane & 15);
        f32x4 v = acc[mi][ni];
        ushort4 o;
        o.x = f2bf(v[0]); o.y = f2bf(v[1]); o.z = f2bf(v[2]); o.w = f2bf(v[3]);
        *reinterpret_cast<ushort4*>(ob + (size_t)d * DD + m) = o;  // e1T[d][m..m+3]
      }
  } else {
    float* ob = (float*)outp + (size_t)b * BE;
    const int mloc = mt * BM + wr * 96 + (lane >> 4) * 4;
    #pragma unroll
    for (int mi = 0; mi < 6; ++mi)
      #pragma unroll
      for (int ni = 0; ni < 6; ++ni) {
        int m = mloc + mi * 16;
        int n = nt * BN_T + wc * 96 + ni * 16 + (lane & 15);
        f32x4 v = acc[mi][ni];
        #pragma unroll
        for (int j = 0; j < 4; ++j) {
          float x = v[j];
          ob[(size_t)(m + j) * DD + n] = x > 0.f ? x : 0.01f * x;
        }
      }
  }
}

// ---------------- launch ----------------

extern "C" void kernel_launch(void* const* d_in, const int* in_sizes, int n_in,
                              void* d_out, int out_size, void* d_ws, size_t ws_size,
                              hipStream_t stream) {
  const float* X   = (const float*)d_in[0];
  const float* adj = (const float*)d_in[1];
  const float* Wl  = (const float*)d_in[2];
  const float* Wl1 = (const float*)d_in[3];
  float* out = (float*)d_out;

  char* ws = (char*)d_ws;
  const size_t SZ = (size_t)BN_ROWS * DD * 2;   // 37,748,736 bytes
  unsigned short* Xb    = (unsigned short*)(ws);
  unsigned short* adjnb = (unsigned short*)(ws + SZ);
  unsigned short* e1T   = (unsigned short*)(ws + 2 * SZ);
  unsigned short* WlT   = (unsigned short*)(ws + 3 * SZ);
  unsigned short* Wl1T  = (unsigned short*)(ws + 3 * SZ + (size_t)BE * 2);

  convertX<<<4096, 256, 0, stream>>>(X, Xb, (BN_ROWS * DD) / 4);
  convertWT<<<144, 256, 0, stream>>>(Wl, Wl1, WlT, Wl1T);
  adjNorm<<<BN_ROWS / 4, 256, 0, stream>>>(adj, adjnb);
  gemm8<0><<<256, 512, 0, stream>>>(Xb, Wl1T, nullptr, nullptr, e1T);
  gemm8<1><<<256, 512, 0, stream>>>(adjnb, e1T, Xb, WlT, out);
}

// Round 6
// 154.906 us; speedup vs baseline: 1.0072x; 1.0072x over previous
//
#include <hip/hip_runtime.h>
#include <hip/hip_bf16.h>
#include <cstdint>
#include <cstddef>

// Problem constants: B=32, N=768, D=768
#define BN_ROWS 24576
#define DD 768
#define BE (768*768)
#define BM 384
#define BN_T 192
#define BK 32
#define ABUF 24576            // A region bytes per buffer (384 rows x 64B)
#define BUFSZ 36864           // A (24576) + B (12288)

typedef __attribute__((ext_vector_type(8))) short bf16x8;
typedef __attribute__((ext_vector_type(4))) float f32x4;

static __device__ __forceinline__ unsigned short f2bf(float f) {
  unsigned int u = __builtin_bit_cast(unsigned int, f);
  unsigned int lsb = (u >> 16) & 1u;
  u += 0x7fffu + lsb;
  return (unsigned short)(u >> 16);
}

// ---------------- conversion kernels ----------------

__global__ __launch_bounds__(256) void convertX(const float* __restrict__ x,
                                                unsigned short* __restrict__ xb, int n4) {
  int idx = blockIdx.x * blockDim.x + threadIdx.x;
  int stride = gridDim.x * blockDim.x;
  for (int i = idx; i < n4; i += stride) {
    float4 v = reinterpret_cast<const float4*>(x)[i];
    ushort4 o;
    o.x = f2bf(v.x); o.y = f2bf(v.y); o.z = f2bf(v.z); o.w = f2bf(v.w);
    reinterpret_cast<ushort4*>(xb)[i] = o;
  }
}

// Transpose+convert via LDS tile (coalesced loads AND stores).
__global__ __launch_bounds__(256) void convertWT(const float* __restrict__ Wl,
                                                 const float* __restrict__ Wl1,
                                                 unsigned short* __restrict__ WlT,
                                                 unsigned short* __restrict__ Wl1T) {
  __shared__ float tile[64][65];
  int tr = blockIdx.x / 12, tc = blockIdx.x % 12;
  int c = threadIdx.x & 63, r0 = threadIdx.x >> 6;
  const float* srcs[2] = {Wl, Wl1};
  unsigned short* dsts[2] = {WlT, Wl1T};
  #pragma unroll
  for (int m = 0; m < 2; ++m) {
    const float* src = srcs[m];
    #pragma unroll
    for (int i = 0; i < 16; ++i) {
      int r = r0 + i * 4;
      tile[r][c] = src[(size_t)(tr * 64 + r) * DD + tc * 64 + c];
    }
    __syncthreads();
    unsigned short* dst = dsts[m];
    #pragma unroll
    for (int i = 0; i < 16; ++i) {
      int r2 = r0 + i * 4;
      dst[(size_t)(tc * 64 + r2) * DD + tr * 64 + c] = f2bf(tile[c][r2]);
    }
    __syncthreads();
  }
}

__global__ __launch_bounds__(256) void adjNorm(const float* __restrict__ adj,
                                               unsigned short* __restrict__ adjnb) {
  int wid = threadIdx.x >> 6, lane = threadIdx.x & 63;
  int row = blockIdx.x * 4 + wid;
  const float4* a = reinterpret_cast<const float4*>(adj + (size_t)row * DD);
  float4 v[3];
  float s = 0.f;
  #pragma unroll
  for (int i = 0; i < 3; ++i) {
    v[i] = a[i * 64 + lane];
    s += (v[i].x + v[i].y) + (v[i].z + v[i].w);
  }
  #pragma unroll
  for (int off = 32; off; off >>= 1) s += __shfl_down(s, off);
  s = __shfl(s, 0);
  float rinv = (s == 0.f) ? 0.f : 1.f / s;
  ushort4* o = reinterpret_cast<ushort4*>(adjnb + (size_t)row * DD);
  #pragma unroll
  for (int i = 0; i < 3; ++i) {
    ushort4 u;
    u.x = f2bf(v[i].x * rinv); u.y = f2bf(v[i].y * rinv);
    u.z = f2bf(v[i].z * rinv); u.w = f2bf(v[i].w * rinv);
    o[i * 64 + lane] = u;
  }
}

// -------- 8-wave 384x192 BK=32 triple-buffered deep-pipeline GEMM --------
// Staging (unchanged from R5): stage(t+2), counted vmcnt(12|6), never 0.
// Tile body (NEW): frag reads in CONSUMPTION order + quadrant MFMA clusters:
//   read a0,b0 ; read a1 ; MFMA Q00(a0,b0) ; read b1 ; MFMA Q10(a1,b0) ;
//   MFMA Q11(a1,b1) ; MFMA Q01(a0,b1)
// -> compiler emits counted lgkmcnt (6/3/0), so quadrants 2-4's LDS reads
// drain UNDER earlier quadrants' MFMA; consecutive quadrants use disjoint
// acc regs (no dep chain). Only the first 6 reads per tile stay exposed.
// MODE 0: e1 = Xb @ W1T, transposed bf16 store (NT=24)
// MODE 1: out = leaky( adjnb@e1 + Xb@Wl ), fused 48-tile K-loop, fp32 store

template<int MODE>
__global__ __launch_bounds__(512, 2) void gemm8(
    const unsigned short* __restrict__ P0,  // MODE0: Xb     MODE1: adjnb
    const unsigned short* __restrict__ P1,  // MODE0: W1T    MODE1: e1T
    const unsigned short* __restrict__ P2,  // MODE1: Xb
    const unsigned short* __restrict__ P3,  // MODE1: WlT
    void* __restrict__ outp)
{
  __shared__ char smem[3 * BUFSZ];
  constexpr int NT = MODE ? 48 : 24;
  const int tid = threadIdx.x, lane = tid & 63;
  const int wid = tid >> 6, wr = wid >> 1, wc = wid & 1;

  // XCD-chunked logical block id (grid 256 = 8 XCD x 32)
  const int logical = (blockIdx.x & 7) * 32 + (blockIdx.x >> 3);

  const unsigned short *Ab0, *Bb0, *Ab1 = nullptr, *Bb1 = nullptr;
  int mt, nt, b;
  if (MODE == 0) {
    mt = logical >> 2; nt = logical & 3;          // mt 0..63, nt 0..3
    b = mt >> 1;
    Ab0 = P0 + (size_t)mt * BM * DD;
    Bb0 = P1 + (size_t)nt * BN_T * DD;
  } else {
    b = logical >> 3; int r = logical & 7; mt = r >> 2; nt = r & 3;
    size_t bo = (size_t)b * BE;
    Ab0 = P0 + bo + (size_t)mt * BM * DD;   // adjnb
    Bb0 = P1 + bo + (size_t)nt * BN_T * DD; // e1T
    Ab1 = P2 + bo + (size_t)mt * BM * DD;   // Xb
    Bb1 = P3 + (size_t)nt * BN_T * DD;      // WlT
  }

  const int r_in = lane >> 2;                 // row within 16-row chunk
  const int s_in = lane & 3;                  // 16B slot

  auto stage = [&](int s) {
    int sc = s < NT ? s : 0;                  // clamp keeps vmcnt uniform
    const int buf = (s % 3) * BUFSZ;
    const unsigned short *Abase, *Bbase;
    int kk;
    if (MODE == 1 && sc >= 24) { kk = sc - 24; Abase = Ab1; Bbase = Bb1; }
    else                       { kk = sc;      Abase = Ab0; Bbase = Bb0; }
    if (wid < 4) {
      #pragma unroll
      for (int i = 0; i < 6; ++i) {
        int row = wid * 96 + i * 16 + r_in;
        int slot = s_in ^ ((row >> 1) & 3);
        const unsigned short* src = Abase + (size_t)row * DD + kk * BK + slot * 8;
        __builtin_amdgcn_global_load_lds(
            (const __attribute__((address_space(1))) void*)src,
            (__attribute__((address_space(3))) void*)(smem + buf + (wid * 96 + i * 16) * 64),
            16, 0, 0);
      }
    } else {
      #pragma unroll
      for (int i = 0; i < 3; ++i) {
        int row = (wid - 4) * 48 + i * 16 + r_in;
        int slot = s_in ^ ((row >> 1) & 3);
        const unsigned short* src = Bbase + (size_t)row * DD + kk * BK + slot * 8;
        __builtin_amdgcn_global_load_lds(
            (const __attribute__((address_space(1))) void*)src,
            (__attribute__((address_space(3))) void*)(smem + buf + ABUF + ((wid - 4) * 48 + i * 16) * 64),
            16, 0, 0);
      }
    }
  };

  const int ks = lane >> 4;                   // k-slot 0..3 (8 elems each)
  auto frag = [&](int off, int row) -> bf16x8 {
    int slot = ks ^ ((row >> 1) & 3);
    return *reinterpret_cast<const bf16x8*>(smem + off + row * 64 + slot * 16);
  };

  f32x4 acc[6][6] = {};

  // prologue: 2 tiles in flight
  stage(0); stage(1);

  for (int t = 0; t < NT; ++t) {
    stage(t + 2);
    if (wid < 4) asm volatile("s_waitcnt vmcnt(12)" ::: "memory");
    else         asm volatile("s_waitcnt vmcnt(6)"  ::: "memory");
    __builtin_amdgcn_s_barrier();

    const int bufA = (t % 3) * BUFSZ;
    const int bufB = bufA + ABUF;
    const int arow = wr * 96 + (lane & 15);
    const int brow = wc * 96 + (lane & 15);

    bf16x8 a0[3], a1[3], b0[3], b1[3];
    // ---- reads in consumption order ----
    #pragma unroll
    for (int i = 0; i < 3; ++i) a0[i] = frag(bufA, arow + i * 16);
    #pragma unroll
    for (int i = 0; i < 3; ++i) b0[i] = frag(bufB, brow + i * 16);
    #pragma unroll
    for (int i = 0; i < 3; ++i) a1[i] = frag(bufA, arow + 48 + i * 16);

    // ---- Q00: a0 x b0 ----
    __builtin_amdgcn_s_setprio(1);
    #pragma unroll
    for (int mi = 0; mi < 3; ++mi)
      #pragma unroll
      for (int ni = 0; ni < 3; ++ni)
        acc[mi][ni] = __builtin_amdgcn_mfma_f32_16x16x32_bf16(a0[mi], b0[ni], acc[mi][ni], 0, 0, 0);
    __builtin_amdgcn_s_setprio(0);

    #pragma unroll
    for (int i = 0; i < 3; ++i) b1[i] = frag(bufB, brow + 48 + i * 16);

    // ---- Q10: a1 x b0 ----
    __builtin_amdgcn_s_setprio(1);
    #pragma unroll
    for (int mi = 0; mi < 3; ++mi)
      #pragma unroll
      for (int ni = 0; ni < 3; ++ni)
        acc[3 + mi][ni] = __builtin_amdgcn_mfma_f32_16x16x32_bf16(a1[mi], b0[ni], acc[3 + mi][ni], 0, 0, 0);

    // ---- Q11: a1 x b1 ----
    #pragma unroll
    for (int mi = 0; mi < 3; ++mi)
      #pragma unroll
      for (int ni = 0; ni < 3; ++ni)
        acc[3 + mi][3 + ni] = __builtin_amdgcn_mfma_f32_16x16x32_bf16(a1[mi], b1[ni], acc[3 + mi][3 + ni], 0, 0, 0);

    // ---- Q01: a0 x b1 ----
    #pragma unroll
    for (int mi = 0; mi < 3; ++mi)
      #pragma unroll
      for (int ni = 0; ni < 3; ++ni)
        acc[mi][3 + ni] = __builtin_amdgcn_mfma_f32_16x16x32_bf16(a0[mi], b1[ni], acc[mi][3 + ni], 0, 0, 0);
    __builtin_amdgcn_s_setprio(0);

    __builtin_amdgcn_s_barrier();
  }

  // ---------------- epilogue ----------------
  if (MODE == 0) {
    unsigned short* ob = (unsigned short*)outp + (size_t)b * BE;
    const int mloc = (mt & 1) * BM + wr * 96 + (lane >> 4) * 4;
    #pragma unroll
    for (int mi = 0; mi < 6; ++mi)
      #pragma unroll
      for (int ni = 0; ni < 6; ++ni) {
        int m = mloc + mi * 16;
        int d = nt * BN_T + wc * 96 + ni * 16 + (lane & 15);
        f32x4 v = acc[mi][ni];
        ushort4 o;
        o.x = f2bf(v[0]); o.y = f2bf(v[1]); o.z = f2bf(v[2]); o.w = f2bf(v[3]);
        *reinterpret_cast<ushort4*>(ob + (size_t)d * DD + m) = o;  // e1T[d][m..m+3]
      }
  } else {
    float* ob = (float*)outp + (size_t)b * BE;
    const int mloc = mt * BM + wr * 96 + (lane >> 4) * 4;
    #pragma unroll
    for (int mi = 0; mi < 6; ++mi)
      #pragma unroll
      for (int ni = 0; ni < 6; ++ni) {
        int m = mloc + mi * 16;
        int n = nt * BN_T + wc * 96 + ni * 16 + (lane & 15);
        f32x4 v = acc[mi][ni];
        #pragma unroll
        for (int j = 0; j < 4; ++j) {
          float x = v[j];
          ob[(size_t)(m + j) * DD + n] = x > 0.f ? x : 0.01f * x;
        }
      }
  }
}

// ---------------- launch ----------------

extern "C" void kernel_launch(void* const* d_in, const int* in_sizes, int n_in,
                              void* d_out, int out_size, void* d_ws, size_t ws_size,
                              hipStream_t stream) {
  const float* X   = (const float*)d_in[0];
  const float* adj = (const float*)d_in[1];
  const float* Wl  = (const float*)d_in[2];
  const float* Wl1 = (const float*)d_in[3];
  float* out = (float*)d_out;

  char* ws = (char*)d_ws;
  const size_t SZ = (size_t)BN_ROWS * DD * 2;   // 37,748,736 bytes
  unsigned short* Xb    = (unsigned short*)(ws);
  unsigned short* adjnb = (unsigned short*)(ws + SZ);
  unsigned short* e1T   = (unsigned short*)(ws + 2 * SZ);
  unsigned short* WlT   = (unsigned short*)(ws + 3 * SZ);
  unsigned short* Wl1T  = (unsigned short*)(ws + 3 * SZ + (size_t)BE * 2);

  convertX<<<4096, 256, 0, stream>>>(X, Xb, (BN_ROWS * DD) / 4);
  convertWT<<<144, 256, 0, stream>>>(Wl, Wl1, WlT, Wl1T);
  adjNorm<<<BN_ROWS / 4, 256, 0, stream>>>(adj, adjnb);
  gemm8<0><<<256, 512, 0, stream>>>(Xb, Wl1T, nullptr, nullptr, e1T);
  gemm8<1><<<256, 512, 0, stream>>>(adjnb, e1T, Xb, WlT, out);
}